// Round 5
// baseline (81.856 us; speedup 1.0000x reference)
//
#include <hip/hip_runtime.h>

#define HW_BIG   1e10f
#define LOSS_EPS 1e-8f

typedef unsigned long long u64;

// ---------------------------------------------------------------------------
// distance (in pixels) to nearest set bit in a 256-bit row mask rm[4] from
// position y. Returns 32768 if the row is empty. Exact.
// ---------------------------------------------------------------------------
__device__ __forceinline__ int row_nearest(const u64* rm, int y) {
    const int yw = y >> 6, yb = y & 63;
    int dd = 32768;
    u64 w = rm[yw] & (~0ULL >> (63 - yb));
    int j = yw;
    while (w == 0 && j > 0) w = rm[--j];
    if (w) dd = y - (j * 64 + 63 - __builtin_clzll(w));
    u64 w2 = rm[yw] & (~0ULL << yb);
    int j2 = yw;
    while (w2 == 0 && j2 < 3) w2 = rm[++j2];
    if (w2) { int du = (j2 * 64 + __builtin_ctzll(w2)) - y; dd = min(dd, du); }
    return dd;
}

// ---------------------------------------------------------------------------
// Kernel 1: block = (img, 4-row group), 1024 threads.
// One load per pixel -> ballot row bitmasks -> word-parallel 4-neighbor
// boundary (zero-padded borders) -> per-pixel row_nearest along y ->
// h[img][x][y] = (nearest boundary bit in row x)^2 as u16 (0xFFFF = empty row
// = exactly BIG). Also stores boundary/label-mask bits and zeroes the
// last-block counter for kernel 2. All global accesses coalesced.
// ---------------------------------------------------------------------------
__global__ void k_masks_h(const float* __restrict__ inp,
                          const float* __restrict__ tgt,
                          u64* __restrict__ rows_bib,
                          u64* __restrict__ rows_blb,
                          u64* __restrict__ rows_ml,
                          unsigned short* __restrict__ h_ib,
                          unsigned short* __restrict__ h_lb,
                          unsigned int* __restrict__ counter) {
    __shared__ u64 V[6][4];     // rows r0..r0+3 (0..3), up-halo (4), down-halo (5)
    __shared__ u64 T[6][4];
    __shared__ u64 Bib[4][4];   // boundary words for own rows
    __shared__ u64 Blb[4][4];
    const int tid = threadIdx.x;
    const int img = blockIdx.x >> 6;
    const int r0  = (blockIdx.x & 63) * 4;
    const int r   = tid >> 8;          // 0..3
    const int y   = tid & 255;
    const int w   = y >> 6;            // word index (uniform per wave)
    const float* ip = inp + (size_t)img * 65536;
    const float* tp = tgt + (size_t)img * 65536;

    if (blockIdx.x == 0 && tid == 0) *counter = 0u;

    const int x = r0 + r;
    bool vb = ip[x * 256 + y] > 0.0f;        // sigmoid(v)>0.5  <=>  v>0
    bool tb = tp[x * 256 + y] > 0.5f;
    u64 bv = __ballot(vb);
    u64 bt = __ballot(tb);
    if ((y & 63) == 0) { V[r][w] = bv; T[r][w] = bt; }

    if (tid < 256) {                          // up halo (border = background)
        const int xh = r0 - 1;
        bool hv = (xh >= 0) && (ip[xh * 256 + y] > 0.0f);
        bool ht = (xh >= 0) && (tp[xh * 256 + y] > 0.5f);
        u64 a = __ballot(hv), b = __ballot(ht);
        if ((y & 63) == 0) { V[4][w] = a; T[4][w] = b; }
    } else if (tid < 512) {                   // down halo
        const int xh = r0 + 4;
        bool hv = (xh < 256) && (ip[xh * 256 + y] > 0.0f);
        bool ht = (xh < 256) && (tp[xh * 256 + y] > 0.5f);
        u64 a = __ballot(hv), b = __ballot(ht);
        if ((y & 63) == 0) { V[5][w] = a; T[5][w] = b; }
    }
    __syncthreads();

    if (tid < 32) {
        const int rr = (tid >> 2) & 3;
        const int j  = tid & 3;
        const bool isT = tid >= 16;
        const u64 (*M)[4] = isT ? T : V;
        u64 own = M[rr][j];
        u64 up  = (rr == 0) ? M[4][j] : M[rr - 1][j];
        u64 dn  = (rr == 3) ? M[5][j] : M[rr + 1][j];
        u64 lf  = (own << 1) | ((j > 0) ? (M[rr][j - 1] >> 63) : 0ULL);
        u64 rt  = (own >> 1) | ((j < 3) ? (M[rr][j + 1] << 63) : 0ULL);
        u64 bnd = own & ~(up & dn & lf & rt);
        const size_t o = ((size_t)img * 256 + (r0 + rr)) * 4 + j;
        if (!isT) { rows_bib[o] = bnd; Bib[rr][j] = bnd; }
        else      { rows_blb[o] = bnd; rows_ml[o] = own; Blb[rr][j] = bnd; }
    }
    __syncthreads();

    const int d1 = row_nearest(&Bib[r][0], y);
    const int d2 = row_nearest(&Blb[r][0], y);
    const size_t o = ((size_t)img * 256 + x) * 256 + y;   // [img][x][y]
    h_ib[o] = (d1 > 255) ? (unsigned short)65535 : (unsigned short)(d1 * d1);
    h_lb[o] = (d2 > 255) ? (unsigned short)65535 : (unsigned short)(d2 * d2);
}

// ---------------------------------------------------------------------------
// Kernel 2 (pass B along x + fused loss + last-block final reduce):
// block = (img, y), thread = x.
//   d2(x,y) = min_{x'} h[x'][y] + (x-x')^2   via exact early-exit outward scan.
// Lanes that don't consume a distance init it to 0 so they don't prolong the
// scan. Weight map + focal BCE, deterministic block reduction -> partials;
// last block to finish does the fixed-order double reduction -> out.
// ---------------------------------------------------------------------------
__global__ void k_passB_loss(const unsigned short* __restrict__ h_ib,
                             const unsigned short* __restrict__ h_lb,
                             const u64* __restrict__ rows_bib,
                             const u64* __restrict__ rows_blb,
                             const u64* __restrict__ rows_ml,
                             const float* __restrict__ inp,
                             float* __restrict__ partials,
                             unsigned int* __restrict__ counter,
                             float* __restrict__ out,
                             int nblk, double inv_count) {
    __shared__ float g1[256];
    __shared__ float g2[256];
    __shared__ float wsum[4];
    __shared__ double dsum[4];
    __shared__ int lastflag;
    const int img = blockIdx.x >> 8;
    const int y   = blockIdx.x & 255;
    const int x   = threadIdx.x;

    // column y of h (layout [img][x'][y]); thread x loads x'=x  (L2 scatter)
    const size_t o = ((size_t)img * 256 + x) * 256 + y;
    {
        unsigned short u1 = h_ib[o];
        unsigned short u2 = h_lb[o];
        g1[x] = (u1 == 65535) ? HW_BIG : (float)u1;
        g2[x] = (u2 == 65535) ? HW_BIG : (float)u2;
    }
    const size_t rbase = (size_t)img * 1024 + (size_t)x * 4 + (y >> 6);
    const u64 wib = rows_bib[rbase];
    const u64 wlb = rows_blb[rbase];
    const u64 wml = rows_ml[rbase];
    const int yb = y & 63;
    const bool fib = (wib >> yb) & 1;
    const bool flb = (wlb >> yb) & 1;
    const float t  = ((wml >> yb) & 1) ? 1.0f : 0.0f;   // target is exactly 0/1
    const float v  = inp[o];
    __syncthreads();

    // exact early-exit outward scan over x' = x -+ d
    float m1 = flb ? g1[x] : 0.0f;   // d2 to image boundary (used only if flb)
    float m2 = fib ? g2[x] : 0.0f;   // d2 to label boundary (used only if fib)
    for (int d = 1; d < 256; ++d) {
        const float fd2 = (float)(d * d);          // exact integer in f32
        if (fd2 >= m1 && fd2 >= m2) break;
        const int xl = x - d;
        if (xl >= 0)  { m1 = fminf(m1, g1[xl] + fd2); m2 = fminf(m2, g2[xl] + fd2); }
        const int xr = x + d;
        if (xr < 256) { m1 = fminf(m1, g1[xr] + fd2); m2 = fminf(m2, g2[xr] + fd2); }
    }

    const float p = 1.0f / (1.0f + expf(-v));
    float wgt = 1.0f;
    if (flb) wgt += expf(-sqrtf(m1));   // THETA=1, SIGMA=1
    if (fib) wgt += expf(-sqrtf(m2));

    // GAMMA = 1
    float loss = wgt * (-(1.0f - p) * t * logf(p + LOSS_EPS)
                        - p * (1.0f - t) * logf(1.0f - p + LOSS_EPS));

    // deterministic block reduction: wave shfl tree + 4 wave partials
    float s = loss;
#pragma unroll
    for (int off = 32; off > 0; off >>= 1) s += __shfl_down(s, off, 64);
    if ((x & 63) == 0) wsum[x >> 6] = s;
    __syncthreads();
    if (x == 0) {
        partials[blockIdx.x] = (wsum[0] + wsum[1]) + (wsum[2] + wsum[3]);
        __threadfence();                         // release partials
        unsigned int old = atomicAdd(counter, 1u);
        lastflag = (old == (unsigned int)(nblk - 1)) ? 1 : 0;
    }
    __syncthreads();

    if (lastflag) {
        __threadfence();                         // acquire all partials
        double ds = 0.0;
        for (int i = x; i < nblk; i += 256) ds += (double)partials[i];
#pragma unroll
        for (int off = 32; off > 0; off >>= 1) ds += __shfl_down(ds, off, 64);
        if ((x & 63) == 0) dsum[x >> 6] = ds;
        __syncthreads();
        if (x == 0) out[0] = (float)(((dsum[0] + dsum[1]) + (dsum[2] + dsum[3])) * inv_count);
    }
}

// ---------------------------------------------------------------------------
extern "C" void kernel_launch(void* const* d_in, const int* in_sizes, int n_in,
                              void* d_out, int out_size, void* d_ws, size_t ws_size,
                              hipStream_t stream) {
    const float* inp = (const float*)d_in[0];
    const float* tgt = (const float*)d_in[1];
    float* out = (float*)d_out;

    const int total = in_sizes[0];          // B*256*256
    const int nimg  = total / 65536;        // B = 8
    const int nblk1 = nimg * 64;            // 512 blocks of 1024 threads
    const int nblk2 = nimg * 256;           // 2048 blocks of 256 threads

    char* ws = (char*)d_ws;
    u64*            rows_bib = (u64*)ws;                               // nimg*1024 u64
    u64*            rows_blb = rows_bib + (size_t)nimg * 1024;
    u64*            rows_ml  = rows_blb + (size_t)nimg * 1024;
    unsigned short* h_ib     = (unsigned short*)(rows_ml + (size_t)nimg * 1024);
    unsigned short* h_lb     = h_ib + (size_t)nimg * 65536;
    float*          parts    = (float*)(h_lb + (size_t)nimg * 65536);
    unsigned int*   counter  = (unsigned int*)(parts + nblk2);

    k_masks_h   <<<nblk1, 1024, 0, stream>>>(inp, tgt, rows_bib, rows_blb, rows_ml,
                                             h_ib, h_lb, counter);
    k_passB_loss<<<nblk2, 256, 0, stream>>>(h_ib, h_lb, rows_bib, rows_blb, rows_ml,
                                            inp, parts, counter, out,
                                            nblk2, 1.0 / (double)total);
}

// Round 6
// 18.897 us; speedup vs baseline: 4.3317x; 4.3317x over previous
//
#include <hip/hip_runtime.h>

#define HW_BIG   1e10f
#define LOSS_EPS 1e-8f

typedef unsigned long long u64;

// ---------------------------------------------------------------------------
// distance (in pixels) to nearest set bit in a 256-bit row mask rm[4] from
// position y. Returns 32768 if the row is empty. Exact.
// ---------------------------------------------------------------------------
__device__ __forceinline__ int row_nearest(const u64* rm, int y) {
    const int yw = y >> 6, yb = y & 63;
    int dd = 32768;
    u64 w = rm[yw] & (~0ULL >> (63 - yb));
    int j = yw;
    while (w == 0 && j > 0) w = rm[--j];
    if (w) dd = y - (j * 64 + 63 - __builtin_clzll(w));
    u64 w2 = rm[yw] & (~0ULL << yb);
    int j2 = yw;
    while (w2 == 0 && j2 < 3) w2 = rm[++j2];
    if (w2) { int du = (j2 * 64 + __builtin_ctzll(w2)) - y; dd = min(dd, du); }
    return dd;
}

// ---------------------------------------------------------------------------
// Kernel 1: block = (img, 4-row group), 1024 threads. One load per pixel ->
// ballot row bitmasks -> word-parallel 4-neighbor boundary (zero-padded
// borders). Outputs row bitmasks only:
//   rows_bib: predicted-image boundary bits (sigmoid(v)>0.5 <=> v>0)
//   rows_blb: label boundary bits           (t>0.5)
//   rows_ml : label mask bits (t is exactly 0/1)
// ---------------------------------------------------------------------------
__global__ void k_masks(const float* __restrict__ inp,
                        const float* __restrict__ tgt,
                        u64* __restrict__ rows_bib,
                        u64* __restrict__ rows_blb,
                        u64* __restrict__ rows_ml) {
    __shared__ u64 V[6][4];     // rows r0..r0+3 (0..3), up-halo (4), down-halo (5)
    __shared__ u64 T[6][4];
    const int tid = threadIdx.x;
    const int img = blockIdx.x >> 6;
    const int r0  = (blockIdx.x & 63) * 4;
    const int r   = tid >> 8;          // 0..3
    const int y   = tid & 255;
    const int w   = y >> 6;            // word index (uniform per wave)
    const float* ip = inp + (size_t)img * 65536;
    const float* tp = tgt + (size_t)img * 65536;

    const int x = r0 + r;
    bool vb = ip[x * 256 + y] > 0.0f;
    bool tb = tp[x * 256 + y] > 0.5f;
    u64 bv = __ballot(vb);
    u64 bt = __ballot(tb);
    if ((y & 63) == 0) { V[r][w] = bv; T[r][w] = bt; }

    if (tid < 256) {                          // up halo (border = background)
        const int xh = r0 - 1;
        bool hv = (xh >= 0) && (ip[xh * 256 + y] > 0.0f);
        bool ht = (xh >= 0) && (tp[xh * 256 + y] > 0.5f);
        u64 a = __ballot(hv), b = __ballot(ht);
        if ((y & 63) == 0) { V[4][w] = a; T[4][w] = b; }
    } else if (tid < 512) {                   // down halo
        const int xh = r0 + 4;
        bool hv = (xh < 256) && (ip[xh * 256 + y] > 0.0f);
        bool ht = (xh < 256) && (tp[xh * 256 + y] > 0.5f);
        u64 a = __ballot(hv), b = __ballot(ht);
        if ((y & 63) == 0) { V[5][w] = a; T[5][w] = b; }
    }
    __syncthreads();

    if (tid < 32) {
        const int rr = (tid >> 2) & 3;
        const int j  = tid & 3;
        const bool isT = tid >= 16;
        const u64 (*M)[4] = isT ? T : V;
        u64 own = M[rr][j];
        u64 up  = (rr == 0) ? M[4][j] : M[rr - 1][j];
        u64 dn  = (rr == 3) ? M[5][j] : M[rr + 1][j];
        u64 lf  = (own << 1) | ((j > 0) ? (M[rr][j - 1] >> 63) : 0ULL);
        u64 rt  = (own >> 1) | ((j < 3) ? (M[rr][j + 1] << 63) : 0ULL);
        u64 bnd = own & ~(up & dn & lf & rt);
        const size_t o = ((size_t)img * 256 + (r0 + rr)) * 4 + j;
        if (!isT) rows_bib[o] = bnd;
        else      { rows_blb[o] = bnd; rows_ml[o] = own; }
    }
}

// ---------------------------------------------------------------------------
// Kernel 2 (DT + loss, no h round-trip): block = (img, 4 output y-rows),
// 1024 threads = (yr = tid>>8, x = tid&255). Whole-image masks in LDS; each
// thread computes G[yr][x] = (nearest boundary bit in row x at position y)^2
// directly in pass-B orientation, then the exact early-exit outward scan over
// x', fused weight + focal BCE, deterministic 16-wave block reduction.
// ---------------------------------------------------------------------------
__global__ void k_dt_loss(const float* __restrict__ inp,
                          const u64* __restrict__ rows_bib,
                          const u64* __restrict__ rows_blb,
                          const u64* __restrict__ rows_ml,
                          float* __restrict__ partials) {
    __shared__ u64 Mib[1024];      // [row x][word] image-boundary bits
    __shared__ u64 Mlb[1024];      // label-boundary bits
    __shared__ u64 Mml[1024];      // label mask bits
    __shared__ float G1[4][256];   // g for the 4 y-rows, indexed [yr][x']
    __shared__ float G2[4][256];
    __shared__ float wsum[16];
    const int tid = threadIdx.x;
    const int img = blockIdx.x >> 6;
    const int y0  = (blockIdx.x & 63) * 4;
    const int yr  = tid >> 8;           // 0..3
    const int x   = tid & 255;
    const int y   = y0 + yr;
    const int yw  = y >> 6, yb = y & 63;

    const size_t mbase = (size_t)img * 1024;
    Mib[tid] = rows_bib[mbase + tid];
    Mlb[tid] = rows_blb[mbase + tid];
    Mml[tid] = rows_ml[mbase + tid];
    // v at (x, y): column-strided read of inp (L2-resident, 2 MB/8 images)
    const float v = inp[((size_t)img * 256 + x) * 256 + y];
    __syncthreads();

    const bool fib = (Mib[x * 4 + yw] >> yb) & 1;
    const bool flb = (Mlb[x * 4 + yw] >> yb) & 1;
    const float t  = ((Mml[x * 4 + yw] >> yb) & 1) ? 1.0f : 0.0f;

    const int d1 = row_nearest(&Mib[x * 4], y);
    const int d2 = row_nearest(&Mlb[x * 4], y);
    G1[yr][x] = (d1 > 255) ? HW_BIG : (float)(d1 * d1);
    G2[yr][x] = (d2 > 255) ? HW_BIG : (float)(d2 * d2);
    __syncthreads();

    // exact early-exit outward scan over x' = x -+ d (per y-row in LDS).
    // Lanes that don't consume a distance (m1 used only where flb, m2 where
    // fib) init to 0 so they never prolong the scan.
    float m1 = flb ? G1[yr][x] : 0.0f;
    float m2 = fib ? G2[yr][x] : 0.0f;
    for (int d = 1; d < 256; ++d) {
        const float fd2 = (float)(d * d);          // exact integer in f32
        if (fd2 >= m1 && fd2 >= m2) break;
        const int xl = x - d;
        if (xl >= 0)  { m1 = fminf(m1, G1[yr][xl] + fd2); m2 = fminf(m2, G2[yr][xl] + fd2); }
        const int xr = x + d;
        if (xr < 256) { m1 = fminf(m1, G1[yr][xr] + fd2); m2 = fminf(m2, G2[yr][xr] + fd2); }
    }

    const float p = 1.0f / (1.0f + expf(-v));
    float wgt = 1.0f;
    if (flb) wgt += expf(-sqrtf(m1));   // THETA=1, SIGMA=1
    if (fib) wgt += expf(-sqrtf(m2));

    // GAMMA = 1
    float loss = wgt * (-(1.0f - p) * t * logf(p + LOSS_EPS)
                        - p * (1.0f - t) * logf(1.0f - p + LOSS_EPS));

    // deterministic block reduction: wave shfl tree + 16 wave partials
    float s = loss;
#pragma unroll
    for (int off = 32; off > 0; off >>= 1) s += __shfl_down(s, off, 64);
    if ((tid & 63) == 0) wsum[tid >> 6] = s;
    __syncthreads();
    if (tid == 0) {
        float bs = 0.0f;
#pragma unroll
        for (int i = 0; i < 16; ++i) bs += wsum[i];
        partials[blockIdx.x] = bs;
    }
}

// ---------------------------------------------------------------------------
// Kernel 3: reduce partials -> mean (single block, fixed order, double accum)
// ---------------------------------------------------------------------------
__global__ void k_reduce(const float* __restrict__ partials, int n,
                         float* __restrict__ out, double inv_count) {
    __shared__ double sw[4];
    const int tid = threadIdx.x;
    double s = 0.0;
    for (int i = tid; i < n; i += 256) s += (double)partials[i];
#pragma unroll
    for (int off = 32; off > 0; off >>= 1) s += __shfl_down(s, off, 64);
    const int lane = tid & 63, wv = tid >> 6;
    if (lane == 0) sw[wv] = s;
    __syncthreads();
    if (tid == 0) out[0] = (float)(((sw[0] + sw[1]) + (sw[2] + sw[3])) * inv_count);
}

// ---------------------------------------------------------------------------
extern "C" void kernel_launch(void* const* d_in, const int* in_sizes, int n_in,
                              void* d_out, int out_size, void* d_ws, size_t ws_size,
                              hipStream_t stream) {
    const float* inp = (const float*)d_in[0];
    const float* tgt = (const float*)d_in[1];
    float* out = (float*)d_out;

    const int total = in_sizes[0];          // B*256*256
    const int nimg  = total / 65536;        // B = 8
    const int nblk  = nimg * 64;            // 512 blocks of 1024 threads

    char* ws = (char*)d_ws;
    u64*   rows_bib = (u64*)ws;                       // nimg*1024 u64 each
    u64*   rows_blb = rows_bib + (size_t)nimg * 1024;
    u64*   rows_ml  = rows_blb + (size_t)nimg * 1024;
    float* parts    = (float*)(rows_ml + (size_t)nimg * 1024);

    k_masks  <<<nblk, 1024, 0, stream>>>(inp, tgt, rows_bib, rows_blb, rows_ml);
    k_dt_loss<<<nblk, 1024, 0, stream>>>(inp, rows_bib, rows_blb, rows_ml, parts);
    k_reduce <<<1,    256,  0, stream>>>(parts, nblk, out, 1.0 / (double)total);
}